// Round 10
// baseline (124.505 us; speedup 1.0000x reference)
//
#include <hip/hip_runtime.h>

#define NPTS 8192
#define BN   16384          // B * N
#define D    32
#define R2   0.0009f        // float32(0.03**2)
#define SIMT 0.7f
#define RAD  0.03f
#define BLOCK 256
#define PBLOCK 512          // pair kernel: 8 waves/block, JSPLIT=2
#define PWAVES 8
#define JSPLIT 2
#define NGRP   (BN / 64)    // 256 i-groups (ISZ stays 64 — R7 lesson)
#define ZBINS 512
#define ZSCALE 1280.0f      // ZBINS / 0.4 (points lie in [0, 0.4))
#define AFIELDS 34          // nbc, cnt, acc[32]
#define CHUNK 512           // j-rows staged per LDS buffer (pts only)

#define GLOBAL_AS __attribute__((address_space(1)))
#define LDS_AS    __attribute__((address_space(3)))

__device__ __forceinline__ void g2lds16(const void* g, void* l) {
  // dst = lds base (wave-uniform) + lane*16; src = per-lane global addr
  __builtin_amdgcn_global_load_lds((const GLOBAL_AS void*)g, (LDS_AS void*)l,
                                   16, 0, 0);
}

// ---------------------------------------------------------------------------
// prep: fused histscan+scatter — R7/R9-verbatim (verified PASS twice).
// Host memset initializes hist+done+pairdone (R8 lesson: cross-dispatch init
// must come from the host stream; persistent magic flags are not
// iteration-safe). Fence-free RELAXED ticket (barrier drains hist RMWs);
// scanner keeps its single release fence to publish the plain-store scans.
// ---------------------------------------------------------------------------
__global__ __launch_bounds__(BLOCK) void prep_kernel(
    const float* __restrict__ pts, const float* __restrict__ emb,
    const int* __restrict__ leaf,
    int* __restrict__ histA, int* __restrict__ histL,
    unsigned* __restrict__ done,
    int* __restrict__ rsA, int* __restrict__ rsL,
    int* __restrict__ curA, int* __restrict__ curL,
    float4* __restrict__ sortedA, int* __restrict__ permA,
    float4* __restrict__ pts4L, float* __restrict__ invL,
    float* __restrict__ embL) {
  const int p = blockIdx.x * BLOCK + threadIdx.x;
  const float x = pts[3 * p + 0];
  const float y = pts[3 * p + 1];
  const float z = pts[3 * p + 2];
  const float sq = x * x + y * y + z * z;
  int bin = (int)(z * ZSCALE); if (bin > ZBINS - 1) bin = ZBINS - 1;
  const int b = p >> 13;
  const int lf = leaf[p] > 0;
  atomicAdd(&histA[b * ZBINS + bin], 1);
  if (lf) atomicAdd(&histL[b * ZBINS + bin], 1);

  float4 er[D / 4];                       // emb row stays in regs to scatter
  float ss = 0.f;
  {
    const float4* __restrict__ e4 = (const float4*)(emb + (size_t)p * D);
#pragma unroll
    for (int i = 0; i < D / 4; ++i) {
      er[i] = e4[i];
      ss += er[i].x * er[i].x + er[i].y * er[i].y +
            er[i].z * er[i].z + er[i].w * er[i].w;
    }
  }
  const float inv = 1.0f / fmaxf(sqrtf(ss), 1e-8f);

  // ---- ticket (fence-free): barrier drains ALL waves' hist RMWs ----
  __shared__ int islast;
  __syncthreads();
  if (threadIdx.x == 0) {
    const unsigned t = __hip_atomic_fetch_add(&done[0], 1u, __ATOMIC_RELAXED,
                                              __HIP_MEMORY_SCOPE_AGENT);
    islast = (t == gridDim.x - 1);
  }
  __syncthreads();

  if (islast) {
    const int wv = threadIdx.x >> 6;    // wave 0..3: {A:b0, A:b1, L:b0, L:b1}
    const int lane = threadIdx.x & 63;
    const int sb = wv & 1;
    const int* __restrict__ h = (wv < 2) ? histA : histL;
    int* __restrict__ rs = (wv < 2) ? rsA : rsL;
    int* __restrict__ cu = (wv < 2) ? curA : curL;
    int carry = 0;
    for (int c = 0; c < ZBINS / 64; ++c) {
      const int idx = c * 64 + lane;
      const int v = __hip_atomic_load(&h[sb * ZBINS + idx], __ATOMIC_RELAXED,
                                      __HIP_MEMORY_SCOPE_AGENT);
      int incl = v;
#pragma unroll
      for (int off = 1; off < 64; off <<= 1) {
        const int t = __shfl_up(incl, off);
        if (lane >= off) incl += t;
      }
      const int excl = carry + incl - v;
      rs[sb * (ZBINS + 1) + idx] = excl;
      cu[sb * ZBINS + idx] = excl;
      carry += __shfl(incl, 63);
    }
    if (lane == 0) rs[sb * (ZBINS + 1) + ZBINS] = carry;  // = leaf/pt totals
    __threadfence();                    // ONE release fence (scanner only)
    __syncthreads();
    if (threadIdx.x == 0)
      __hip_atomic_store(&done[1], 1u, __ATOMIC_RELEASE,
                         __HIP_MEMORY_SCOPE_AGENT);
  } else {
    if (threadIdx.x == 0) {
      while (__hip_atomic_load(&done[1], __ATOMIC_ACQUIRE,
                               __HIP_MEMORY_SCOPE_AGENT) == 0)
        __builtin_amdgcn_s_sleep(8);
    }
    __syncthreads();
  }

  // ---- scatter phase (cursors via coherent atomics) ----
  const int dst = b * NPTS + atomicAdd(&curA[b * ZBINS + bin], 1);
  sortedA[dst] = make_float4(x, y, z, lf ? inv : -inv);  // leaf in sign bit
  permA[dst] = p;

  if (lf) {
    const int dl = b * NPTS + atomicAdd(&curL[b * ZBINS + bin], 1);
    pts4L[dl] = make_float4(x, y, z, 0.5f * (sq - R2));
    invL[dl] = inv;
    float4* __restrict__ d4 = (float4*)(embL + (size_t)dl * D);
#pragma unroll
    for (int k = 0; k < D / 4; ++k) d4[k] = er[k];
  }
}

// ---------------------------------------------------------------------------
// pair + fused reduce/MLP — R18: JSPLIT=2 without fences. Occupancy 21-27%
// across every healthy pair variant says mean/makespan ~= 0.5: the densest
// z-window blocks set a ~2x tail while most CUs idle. Each group's window
// now splits across 2 blocks of 8 waves (512 blocks, 2/CU; rows/wave
// unchanged at len/16; staged rows total unchanged; ISZ stays 64 so per-
// group setup count stays 256x2 not 512x setup-heavy — R7 lesson). Merge
// WITHOUT __threadfence (R2/R5's 0.3us/block killer): publish the local
// red[34][64] to a private accG slot via device-scope RELAXED ATOMIC stores
// (atomics complete at the coherence point; __syncthreads drains vmcnt —
// R7-validated reasoning), RELAXED ticket, SECOND arriver merges both slots
// into LDS and runs the R9-proven 4-wave MLP epilogue. accG needs no init
// (both slots fully overwritten before read); pairdone is host-memset.
// ---------------------------------------------------------------------------
__global__ __launch_bounds__(PBLOCK) void pair_kernel(
    const float4* __restrict__ sortedA, const int* __restrict__ permA,
    const float4* __restrict__ pts4L, const float* __restrict__ invL,
    const float* __restrict__ embL, const float* __restrict__ emb,
    const int* __restrict__ rsL,
    const float* __restrict__ W1, const float* __restrict__ b1,
    const float* __restrict__ W2, const float* __restrict__ b2,
    float* __restrict__ accG, int* __restrict__ pairdone,
    float* __restrict__ out) {
  const int bid  = blockIdx.x;
  const int ig   = bid >> 1;              // i-group of 64 (0..255)
  const int js   = bid & 1;               // which window half
  const int b    = ig >> 7;               // 128 i-groups per batch
  const int lane = threadIdx.x & 63;
  const int wv   = threadIdx.x >> 6;      // wave 0..7
  const int sg   = ig * 64 + lane;

  __shared__ __align__(16) float4 ptsS[2][CHUNK];   // 16 KB
  __shared__ __align__(16) float4 eiS4[64 * 8];     //  8 KB, XOR-swizzled
  __shared__ float invIS[64];
  __shared__ int   queueS[PWAVES][128];             //  4 KB ring/wave
  __shared__ float red[AFIELDS][64];                //  8.7 KB
  __shared__ float hS[D][64];                       //  8 KB (epilogue)
  __shared__ int   islast;
  for (int t = threadIdx.x; t < AFIELDS * 64; t += PBLOCK)
    (&red[0][0])[t] = 0.f;

  const float4 A = sortedA[sg];
  const float inv_i = fabsf(A.w);
  const float mhsq = -0.5f * (A.x * A.x + A.y * A.y + A.z * A.z);
  const int p = permA[sg];

  if (wv == 0) {                          // block-shared e_i copy (swizzled)
    const float4* __restrict__ e4 = (const float4*)(emb + (size_t)p * D);
#pragma unroll
    for (int k = 0; k < D / 4; ++k) eiS4[lane * 8 + (k ^ (lane & 7))] = e4[k];
    invIS[lane] = inv_i;
  }

  float zmin = A.z, zmax = A.z;
#pragma unroll
  for (int off = 1; off < 64; off <<= 1) {
    zmin = fminf(zmin, __shfl_xor(zmin, off));
    zmax = fmaxf(zmax, __shfl_xor(zmax, off));
  }
  int klo = (int)((zmin - RAD) * ZSCALE) - 1; if (klo < 0) klo = 0;  // fp slack
  int khi = (int)((zmax + RAD) * ZSCALE) + 1; if (khi > ZBINS - 1) khi = ZBINS - 1;
  klo = __builtin_amdgcn_readfirstlane(klo);
  khi = __builtin_amdgcn_readfirstlane(khi);
  const int jlo = b * NPTS + rsL[b * (ZBINS + 1) + klo];
  const int jhi = b * NPTS + rsL[b * (ZBINS + 1) + khi + 1];
  const int len = jhi - jlo;              // block-uniform
  int blo = jlo + (len * js) / JSPLIT;    // this block's half-window
  int bhi = jlo + (len * (js + 1)) / JSPLIT;
  blo = __builtin_amdgcn_readfirstlane(blo);
  bhi = __builtin_amdgcn_readfirstlane(bhi);
  const int blen = bhi - blo;

  float nbc = 0.f;
  int qtail = 0, qdone = 0;

  const float4* __restrict__ embQ = (const float4*)embL;

  // ---- drain n (<=64) queued pairs: one pair per lane, dense ----
  auto drain = [&](int n) {
    if (lane < n) {
      const int e  = queueS[wv][(qdone + lane) & 127];
      const int il = e & 63;
      const int j  = e >> 6;
      float4 bv[D / 4];
#pragma unroll
      for (int k = 0; k < D / 4; ++k) bv[k] = embQ[(size_t)j * 8 + k];
      const float invj = invL[j];
      float s0 = 0.f, s1 = 0.f, s2 = 0.f, s3 = 0.f;
#pragma unroll
      for (int k = 0; k < D / 4; ++k) {
        const float4 av = eiS4[il * 8 + (k ^ (il & 7))];
        s0 = fmaf(av.x, bv[k].x, s0);
        s1 = fmaf(av.y, bv[k].y, s1);
        s2 = fmaf(av.z, bv[k].z, s2);
        s3 = fmaf(av.w, bv[k].w, s3);
      }
      const float sim = ((s0 + s1) + (s2 + s3)) * invIS[il] * invj;
      if (sim > SIMT) {                   // rare (mostly self-pairs)
        atomicAdd(&red[1][il], 1.0f);
#pragma unroll
        for (int k = 0; k < D / 4; ++k) {
          atomicAdd(&red[2 + 4 * k + 0][il], bv[k].x);
          atomicAdd(&red[2 + 4 * k + 1][il], bv[k].y);
          atomicAdd(&red[2 + 4 * k + 2][il], bv[k].z);
          atomicAdd(&red[2 + 4 * k + 3][il], bv[k].w);
        }
      }
    }
    qdone += n;
  };

  // ---- async stage of one pts chunk ----
  auto stage = [&](int buf, int base, int L) {
    for (int t0 = wv * 64; t0 < L; t0 += PWAVES * 64)
      g2lds16((const char*)pts4L + (((size_t)(base + t0 + lane)) << 4),
              &ptsS[buf][t0]);
  };

  // ---- geometric pass over this wave's slice of the staged chunk ----
  auto process = [&](int buf, int jbase, int L) {
    const int s0 = (L * wv) / PWAVES;
    const int s1 = (L * (wv + 1)) / PWAVES;
    if (s0 >= s1) return;
    float4 c = ptsS[buf][s0];
    for (int jl = s0; jl < s1; ++jl) {
      const float4 cn = ptsS[buf][(jl + 1 < s1) ? (jl + 1) : s0];
      const float t = fmaf(A.z, c.z, fmaf(A.y, c.y, fmaf(A.x, c.x, mhsq)));
      const bool hit = t > c.w;           // d2 < R2; j is leaf by construction
      const unsigned long long m = __ballot(hit);
      if (m) {
        if (hit) {
          nbc += 1.0f;
          const int below = __popcll(m & ((1ull << lane) - 1ull));
          queueS[wv][(qtail + below) & 127] = ((jbase + jl) << 6) | lane;
        }
        qtail += (int)__popcll(m);        // uniform, no atomics
        if (qtail - qdone >= 64) drain(64);
      }
      c = cn;
    }
  };

  const int nch = (blen + CHUNK - 1) / CHUNK;
  if (nch > 0) stage(0, blo, (blen < CHUNK) ? blen : CHUNK);
  __syncthreads();                        // red/eiS init + chunk 0 ready
  for (int k = 0; k < nch; ++k) {
    const int cur = k & 1;
    if (k + 1 < nch) {
      const int base = blo + (k + 1) * CHUNK;
      const int L = (bhi - base < CHUNK) ? (bhi - base) : CHUNK;
      stage(cur ^ 1, base, L);            // async; overlaps with process
    }
    const int base = blo + k * CHUNK;
    const int Lc = (bhi - base < CHUNK) ? (bhi - base) : CHUNK;
    process(cur, base, Lc);
    __syncthreads();                      // staged data ready + cur free
  }
  drain(qtail - qdone);                   // final flush (<64)

  if (nbc != 0.f) atomicAdd(&red[0][lane], nbc);
  __syncthreads();                        // local reduce complete

  // ---- publish partial slice via device-scope ATOMIC stores (no fence) ----
  {
    float* __restrict__ slot = accG + (size_t)bid * (AFIELDS * 64);
    const float* __restrict__ rf = &red[0][0];
    for (int t = threadIdx.x; t < AFIELDS * 64; t += PBLOCK)
      __hip_atomic_store(&slot[t], rf[t], __ATOMIC_RELAXED,
                         __HIP_MEMORY_SCOPE_AGENT);
  }
  __syncthreads();                        // drains the atomic stores (vmcnt)
  if (threadIdx.x == 0) {
    const unsigned t = __hip_atomic_fetch_add(
        (unsigned*)&pairdone[ig], 1u, __ATOMIC_RELAXED,
        __HIP_MEMORY_SCOPE_AGENT);
    islast = (t == JSPLIT - 1);
  }
  __syncthreads();
  if (!islast) return;                    // first arriver exits

  // ---- second arriver: merge both slots back into LDS ----
  {
    const float* __restrict__ s0 = accG + (size_t)(ig * 2 + 0) * (AFIELDS * 64);
    const float* __restrict__ s1 = accG + (size_t)(ig * 2 + 1) * (AFIELDS * 64);
    float* __restrict__ rf = &red[0][0];
    for (int t = threadIdx.x; t < AFIELDS * 64; t += PBLOCK)
      rf[t] = __hip_atomic_load(&s0[t], __ATOMIC_RELAXED,
                                __HIP_MEMORY_SCOPE_AGENT) +
              __hip_atomic_load(&s1[t], __ATOMIC_RELAXED,
                                __HIP_MEMORY_SCOPE_AGENT);
  }
  __syncthreads();

  // ---- epilogue phase A: waves 0..3, h k-slices (lane = point) ----
  const int kk0 = wv * 8;
  if (wv < 4) {
    const float tcnt = red[1][lane];
    const float rinv = 1.0f / fmaxf(tcnt, 1.0f);
    float h[8];
#pragma unroll
    for (int k = 0; k < 8; ++k) h[k] = b1[kk0 + k];
#pragma unroll
    for (int d = 0; d < D; ++d) {
      const float4 v = eiS4[lane * 8 + ((d >> 2) ^ (lane & 7))];
      const float c = ((d & 3) == 0) ? v.x : ((d & 3) == 1) ? v.y
                    : ((d & 3) == 2) ? v.z : v.w;
      const float* __restrict__ w = W1 + (size_t)d * D + kk0;
#pragma unroll
      for (int k = 0; k < 8; ++k) h[k] = fmaf(c, w[k], h[k]);
    }
#pragma unroll
    for (int d = 0; d < D; ++d) {
      const float c = red[2 + d][lane] * rinv;    // mean_sim[d]
      const float* __restrict__ w = W1 + (size_t)(D + d) * D + kk0;
#pragma unroll
      for (int k = 0; k < 8; ++k) h[k] = fmaf(c, w[k], h[k]);
    }
#pragma unroll
    for (int k = 0; k < 8; ++k) hS[kk0 + k][lane] = fmaxf(h[k], 0.f);
  }
  __syncthreads();                        // all 8 waves

  // ---- epilogue phase B: waves 0..3, o k-slices + output quarter ----
  if (wv < 4) {
    float o[8];
#pragma unroll
    for (int m = 0; m < 8; ++m) o[m] = b2[kk0 + m];
#pragma unroll
    for (int k = 0; k < D; ++k) {
      const float hv = hS[k][lane];       // lane-contiguous, conflict-free
      const float* __restrict__ w = W2 + (size_t)k * D + kk0;
#pragma unroll
      for (int m = 0; m < 8; ++m) o[m] = fmaf(hv, w[m], o[m]);
    }
    const float tnbc = red[0][lane];
    const float tcnt = red[1][lane];
    const bool lf = A.w > 0.f;
    const int nleaf = rsL[b * (ZBINS + 1) + ZBINS];  // scan carry = leaf total
    const bool cond = lf && (tnbc >= 2.0f) && (tcnt >= 1.0f) && (nleaf >= 10);

    float4* outr = (float4*)(out + (size_t)p * D + kk0);
#pragma unroll
    for (int i = 0; i < 2; ++i) {
      float4 v;
      if (cond) { v.x = o[4*i+0]; v.y = o[4*i+1]; v.z = o[4*i+2]; v.w = o[4*i+3]; }
      else      { v = eiS4[lane * 8 + (((kk0 >> 2) + i) ^ (lane & 7))]; }
      outr[i] = v;
    }
  }
}

// ---------------------------------------------------------------------------
extern "C" void kernel_launch(void* const* d_in, const int* in_sizes, int n_in,
                              void* d_out, int out_size, void* d_ws, size_t ws_size,
                              hipStream_t stream) {
  (void)in_sizes; (void)n_in; (void)out_size; (void)ws_size;
  const float* pts  = (const float*)d_in[0];
  const float* emb  = (const float*)d_in[1];
  const int*   leaf = (const int*)d_in[2];
  const float* W1   = (const float*)d_in[3];
  const float* b1   = (const float*)d_in[4];
  const float* W2   = (const float*)d_in[5];
  const float* b2   = (const float*)d_in[6];
  float* out = (float*)d_out;

  char* ws = (char*)d_ws;
  size_t off = 0;
  auto alloc = [&](size_t bytes) { void* r = ws + off; off = (off + bytes + 15) & ~(size_t)15; return r; };

  // +CHUNK rows of slack on j-side arrays: staging rounds up to 64-lane
  // granularity and may read past jhi; slack keeps those reads in-bounds.
  float4*   sortedA = (float4*)alloc((size_t)BN * 16);
  int*      permA   = (int*)alloc((size_t)BN * 4);
  float4*   pts4L   = (float4*)alloc((size_t)(BN + CHUNK) * 16);
  float*    invL    = (float*)alloc((size_t)(BN + CHUNK) * 4);
  float*    embL    = (float*)alloc((size_t)(BN + CHUNK) * D * 4);
  float*    accG    = (float*)alloc((size_t)NGRP * JSPLIT * AFIELDS * 64 * 4);
  int*      rsA     = (int*)alloc(2 * (ZBINS + 1) * 4);
  int*      rsL     = (int*)alloc(2 * (ZBINS + 1) * 4);
  int*      curA    = (int*)alloc(2 * ZBINS * 4);
  int*      curL    = (int*)alloc(2 * ZBINS * 4);
  int*      histA   = (int*)alloc(2 * ZBINS * 4);   // histA..pairdone contiguous
  int*      histL   = (int*)alloc(2 * ZBINS * 4);   //   -> single 9.2 KB memset
  unsigned* done    = (unsigned*)alloc(16);          // [0]=ticket [1]=scan flag
  int*      pairdone= (int*)alloc(NGRP * 4);

  // memset covers histA(4K) + histL(4K) + done(16) + pairdone(1K); accG needs
  // no init (both slots fully overwritten each invocation before any read).
  hipMemsetAsync(histA, 0, 2 * (2 * ZBINS * 4) + 16 + NGRP * 4, stream);
  prep_kernel<<<BN / BLOCK, BLOCK, 0, stream>>>(
      pts, emb, leaf, histA, histL, done, rsA, rsL, curA, curL,
      sortedA, permA, pts4L, invL, embL);
  pair_kernel<<<NGRP * JSPLIT, PBLOCK, 0, stream>>>(
      sortedA, permA, pts4L, invL, embL, emb, rsL,
      W1, b1, W2, b2, accG, pairdone, out);
}

// Round 11
// 106.764 us; speedup vs baseline: 1.1662x; 1.1662x over previous
//
#include <hip/hip_runtime.h>

#define NPTS 8192
#define BN   16384          // B * N
#define D    32
#define R2   0.0009f        // float32(0.03**2)
#define SIMT 0.7f
#define RAD  0.03f
#define BLOCK 256
#define PBLOCK 1024         // pair kernel: 16 waves/block (proven R12 shape)
#define PWAVES 16
#define NGRP   (BN / 64)    // 256 i-groups, 1 block each
#define ZBINS 512
#define ZSCALE 1280.0f      // ZBINS / 0.4 (points lie in [0, 0.4))
#define AFIELDS 34          // nbc, cnt, acc[32]
#define CHUNK 512           // j-rows staged per LDS buffer (pts only)

#define GLOBAL_AS __attribute__((address_space(1)))
#define LDS_AS    __attribute__((address_space(3)))

__device__ __forceinline__ void g2lds16(const void* g, void* l) {
  // dst = lds base (wave-uniform) + lane*16; src = per-lane global addr
  __builtin_amdgcn_global_load_lds((const GLOBAL_AS void*)g, (LDS_AS void*)l,
                                   16, 0, 0);
}

// ---------------------------------------------------------------------------
// prep: fused histscan+scatter — R7/R9-verbatim (verified PASS twice at the
// session best). Host memset initializes hist+done (R8 lesson: cross-
// dispatch init must come from the host stream; persistent magic flags are
// not iteration-safe — a stale flag let replay blocks pass the gate before
// re-zeroing, OOB scatter, core dump). Fence-free RELAXED ticket (the
// barrier drains all waves' hist RMWs to the coherence point — R7-
// validated); scanner keeps its single release fence to publish the
// plain-store scan results to the other 63 spinning blocks.
// ---------------------------------------------------------------------------
__global__ __launch_bounds__(BLOCK) void prep_kernel(
    const float* __restrict__ pts, const float* __restrict__ emb,
    const int* __restrict__ leaf,
    int* __restrict__ histA, int* __restrict__ histL,
    unsigned* __restrict__ done,
    int* __restrict__ rsA, int* __restrict__ rsL,
    int* __restrict__ curA, int* __restrict__ curL,
    float4* __restrict__ sortedA, int* __restrict__ permA,
    float4* __restrict__ pts4L, float* __restrict__ invL,
    float* __restrict__ embL) {
  const int p = blockIdx.x * BLOCK + threadIdx.x;
  const float x = pts[3 * p + 0];
  const float y = pts[3 * p + 1];
  const float z = pts[3 * p + 2];
  const float sq = x * x + y * y + z * z;
  int bin = (int)(z * ZSCALE); if (bin > ZBINS - 1) bin = ZBINS - 1;
  const int b = p >> 13;
  const int lf = leaf[p] > 0;
  atomicAdd(&histA[b * ZBINS + bin], 1);
  if (lf) atomicAdd(&histL[b * ZBINS + bin], 1);

  float4 er[D / 4];                       // emb row stays in regs to scatter
  float ss = 0.f;
  {
    const float4* __restrict__ e4 = (const float4*)(emb + (size_t)p * D);
#pragma unroll
    for (int i = 0; i < D / 4; ++i) {
      er[i] = e4[i];
      ss += er[i].x * er[i].x + er[i].y * er[i].y +
            er[i].z * er[i].z + er[i].w * er[i].w;
    }
  }
  const float inv = 1.0f / fmaxf(sqrtf(ss), 1e-8f);

  // ---- ticket (fence-free): barrier drains ALL waves' hist RMWs to the
  // coherence point before thread 0 increments the ticket (validated R7). ----
  __shared__ int islast;
  __syncthreads();
  if (threadIdx.x == 0) {
    const unsigned t = __hip_atomic_fetch_add(&done[0], 1u, __ATOMIC_RELAXED,
                                              __HIP_MEMORY_SCOPE_AGENT);
    islast = (t == gridDim.x - 1);
  }
  __syncthreads();

  if (islast) {
    const int wv = threadIdx.x >> 6;    // wave 0..3: {A:b0, A:b1, L:b0, L:b1}
    const int lane = threadIdx.x & 63;
    const int sb = wv & 1;
    const int* __restrict__ h = (wv < 2) ? histA : histL;
    int* __restrict__ rs = (wv < 2) ? rsA : rsL;
    int* __restrict__ cu = (wv < 2) ? curA : curL;
    int carry = 0;
    for (int c = 0; c < ZBINS / 64; ++c) {
      const int idx = c * 64 + lane;
      const int v = __hip_atomic_load(&h[sb * ZBINS + idx], __ATOMIC_RELAXED,
                                      __HIP_MEMORY_SCOPE_AGENT);
      int incl = v;
#pragma unroll
      for (int off = 1; off < 64; off <<= 1) {
        const int t = __shfl_up(incl, off);
        if (lane >= off) incl += t;
      }
      const int excl = carry + incl - v;
      rs[sb * (ZBINS + 1) + idx] = excl;
      cu[sb * ZBINS + idx] = excl;
      carry += __shfl(incl, 63);
    }
    if (lane == 0) rs[sb * (ZBINS + 1) + ZBINS] = carry;  // = leaf/pt totals
    __threadfence();                    // ONE release fence (scanner only)
    __syncthreads();
    if (threadIdx.x == 0)
      __hip_atomic_store(&done[1], 1u, __ATOMIC_RELEASE,
                         __HIP_MEMORY_SCOPE_AGENT);
  } else {
    if (threadIdx.x == 0) {
      while (__hip_atomic_load(&done[1], __ATOMIC_ACQUIRE,
                               __HIP_MEMORY_SCOPE_AGENT) == 0)
        __builtin_amdgcn_s_sleep(8);
    }
    __syncthreads();
  }

  // ---- scatter phase (cursors via coherent atomics) ----
  const int dst = b * NPTS + atomicAdd(&curA[b * ZBINS + bin], 1);
  sortedA[dst] = make_float4(x, y, z, lf ? inv : -inv);  // leaf in sign bit
  permA[dst] = p;

  if (lf) {
    const int dl = b * NPTS + atomicAdd(&curL[b * ZBINS + bin], 1);
    pts4L[dl] = make_float4(x, y, z, 0.5f * (sq - R2));
    invL[dl] = inv;
    float4* __restrict__ d4 = (float4*)(embL + (size_t)dl * D);
#pragma unroll
    for (int k = 0; k < D / 4; ++k) d4[k] = er[k];
  }
}

// ---------------------------------------------------------------------------
// pair + fused reduce/MLP — R9-verbatim (session best, 108.3us total).
// Design-family conclusions baked in (do not revisit):
//  * 256 monolithic blocks x 16 waves is optimal: window-splitting with
//    cross-block merge was tried twice and lost both times (R10 fence-free
//    atomic publish: +16us; R5 fence-based: +170us). The ~10us straggler
//    tail is cheaper than any merge machinery built to remove it.
//  * 64-i groups amortize per-group setup 2x better than 32-i (R7: -40us).
//  * No device fences in this kernel ever (R5: ~0.3us/block serialized).
//  * Queue-compaction (geometric pass -> per-wave LDS queue -> dense
//    64-pair drain) beats broadcast-dot by ~1.6x (R4 vs R3: LDS pipe was
//    the wall at ~2% lane utilization).
//  * 4-wave sliced MLP epilogue beats wave-0-serial by ~6.8us total (R9).
// ---------------------------------------------------------------------------
__global__ __launch_bounds__(PBLOCK) void pair_kernel(
    const float4* __restrict__ sortedA, const int* __restrict__ permA,
    const float4* __restrict__ pts4L, const float* __restrict__ invL,
    const float* __restrict__ embL, const float* __restrict__ emb,
    const int* __restrict__ rsL,
    const float* __restrict__ W1, const float* __restrict__ b1,
    const float* __restrict__ W2, const float* __restrict__ b2,
    float* __restrict__ out) {
  const int ig   = blockIdx.x;            // i-group of 64 (0..255)
  const int b    = ig >> 7;               // 128 i-groups per batch
  const int lane = threadIdx.x & 63;
  const int wv   = threadIdx.x >> 6;      // wave 0..15
  const int sg   = ig * 64 + lane;

  __shared__ __align__(16) float4 ptsS[2][CHUNK];   // 16 KB
  __shared__ __align__(16) float4 eiS4[64 * 8];     //  8 KB, XOR-swizzled
  __shared__ float invIS[64];
  __shared__ int   queueS[PWAVES][128];             //  8 KB ring/wave
  __shared__ float red[AFIELDS][64];                //  8.7 KB
  __shared__ float hS[D][64];                       //  8 KB (epilogue)
  for (int t = threadIdx.x; t < AFIELDS * 64; t += PBLOCK)
    (&red[0][0])[t] = 0.f;

  const float4 A = sortedA[sg];
  const float inv_i = fabsf(A.w);
  const float mhsq = -0.5f * (A.x * A.x + A.y * A.y + A.z * A.z);
  const int p = permA[sg];

  if (wv == 0) {                          // block-shared e_i copy (swizzled)
    const float4* __restrict__ e4 = (const float4*)(emb + (size_t)p * D);
#pragma unroll
    for (int k = 0; k < D / 4; ++k) eiS4[lane * 8 + (k ^ (lane & 7))] = e4[k];
    invIS[lane] = inv_i;
  }

  float zmin = A.z, zmax = A.z;
#pragma unroll
  for (int off = 1; off < 64; off <<= 1) {
    zmin = fminf(zmin, __shfl_xor(zmin, off));
    zmax = fmaxf(zmax, __shfl_xor(zmax, off));
  }
  int klo = (int)((zmin - RAD) * ZSCALE) - 1; if (klo < 0) klo = 0;  // fp slack
  int khi = (int)((zmax + RAD) * ZSCALE) + 1; if (khi > ZBINS - 1) khi = ZBINS - 1;
  klo = __builtin_amdgcn_readfirstlane(klo);
  khi = __builtin_amdgcn_readfirstlane(khi);
  const int jlo = b * NPTS + rsL[b * (ZBINS + 1) + klo];
  const int jhi = b * NPTS + rsL[b * (ZBINS + 1) + khi + 1];
  const int len = jhi - jlo;              // block-uniform

  float nbc = 0.f;
  int qtail = 0, qdone = 0;

  const float4* __restrict__ embQ = (const float4*)embL;

  // ---- drain n (<=64) queued pairs: one pair per lane, dense ----
  auto drain = [&](int n) {
    if (lane < n) {
      const int e  = queueS[wv][(qdone + lane) & 127];
      const int il = e & 63;
      const int j  = e >> 6;
      float4 bv[D / 4];
#pragma unroll
      for (int k = 0; k < D / 4; ++k) bv[k] = embQ[(size_t)j * 8 + k];
      const float invj = invL[j];
      float s0 = 0.f, s1 = 0.f, s2 = 0.f, s3 = 0.f;
#pragma unroll
      for (int k = 0; k < D / 4; ++k) {
        const float4 av = eiS4[il * 8 + (k ^ (il & 7))];
        s0 = fmaf(av.x, bv[k].x, s0);
        s1 = fmaf(av.y, bv[k].y, s1);
        s2 = fmaf(av.z, bv[k].z, s2);
        s3 = fmaf(av.w, bv[k].w, s3);
      }
      const float sim = ((s0 + s1) + (s2 + s3)) * invIS[il] * invj;
      if (sim > SIMT) {                   // rare (mostly self-pairs)
        atomicAdd(&red[1][il], 1.0f);
#pragma unroll
        for (int k = 0; k < D / 4; ++k) {
          atomicAdd(&red[2 + 4 * k + 0][il], bv[k].x);
          atomicAdd(&red[2 + 4 * k + 1][il], bv[k].y);
          atomicAdd(&red[2 + 4 * k + 2][il], bv[k].z);
          atomicAdd(&red[2 + 4 * k + 3][il], bv[k].w);
        }
      }
    }
    qdone += n;
  };

  // ---- async stage of one pts chunk ----
  auto stage = [&](int buf, int base, int L) {
    for (int t0 = wv * 64; t0 < L; t0 += PWAVES * 64)
      g2lds16((const char*)pts4L + (((size_t)(base + t0 + lane)) << 4),
              &ptsS[buf][t0]);
  };

  // ---- geometric pass over this wave's slice of the staged chunk ----
  auto process = [&](int buf, int jbase, int L) {
    const int s0 = (L * wv) / PWAVES;
    const int s1 = (L * (wv + 1)) / PWAVES;
    if (s0 >= s1) return;
    float4 c = ptsS[buf][s0];
    for (int jl = s0; jl < s1; ++jl) {
      const float4 cn = ptsS[buf][(jl + 1 < s1) ? (jl + 1) : s0];
      const float t = fmaf(A.z, c.z, fmaf(A.y, c.y, fmaf(A.x, c.x, mhsq)));
      const bool hit = t > c.w;           // d2 < R2; j is leaf by construction
      const unsigned long long m = __ballot(hit);
      if (m) {
        if (hit) {
          nbc += 1.0f;
          const int below = __popcll(m & ((1ull << lane) - 1ull));
          queueS[wv][(qtail + below) & 127] = ((jbase + jl) << 6) | lane;
        }
        qtail += (int)__popcll(m);        // uniform, no atomics
        if (qtail - qdone >= 64) drain(64);
      }
      c = cn;
    }
  };

  const int nch = (len + CHUNK - 1) / CHUNK;
  if (nch > 0) stage(0, jlo, (len < CHUNK) ? len : CHUNK);
  __syncthreads();                        // red/eiS init + chunk 0 ready
  for (int k = 0; k < nch; ++k) {
    const int cur = k & 1;
    if (k + 1 < nch) {
      const int base = jlo + (k + 1) * CHUNK;
      const int L = (jhi - base < CHUNK) ? (jhi - base) : CHUNK;
      stage(cur ^ 1, base, L);            // async; overlaps with process
    }
    const int base = jlo + k * CHUNK;
    const int Lc = (jhi - base < CHUNK) ? (jhi - base) : CHUNK;
    process(cur, base, Lc);
    __syncthreads();                      // staged data ready + cur free
  }
  drain(qtail - qdone);                   // final flush (<64)

  if (nbc != 0.f) atomicAdd(&red[0][lane], nbc);
  __syncthreads();

  // ---- epilogue phase A: waves 0..3, h k-slices (lane = point) ----
  const int kk0 = wv * 8;
  if (wv < 4) {
    const float tcnt = red[1][lane];
    const float rinv = 1.0f / fmaxf(tcnt, 1.0f);
    float h[8];
#pragma unroll
    for (int k = 0; k < 8; ++k) h[k] = b1[kk0 + k];
#pragma unroll
    for (int d = 0; d < D; ++d) {
      const float4 v = eiS4[lane * 8 + ((d >> 2) ^ (lane & 7))];
      const float c = ((d & 3) == 0) ? v.x : ((d & 3) == 1) ? v.y
                    : ((d & 3) == 2) ? v.z : v.w;
      const float* __restrict__ w = W1 + (size_t)d * D + kk0;
#pragma unroll
      for (int k = 0; k < 8; ++k) h[k] = fmaf(c, w[k], h[k]);
    }
#pragma unroll
    for (int d = 0; d < D; ++d) {
      const float c = red[2 + d][lane] * rinv;    // mean_sim[d]
      const float* __restrict__ w = W1 + (size_t)(D + d) * D + kk0;
#pragma unroll
      for (int k = 0; k < 8; ++k) h[k] = fmaf(c, w[k], h[k]);
    }
#pragma unroll
    for (int k = 0; k < 8; ++k) hS[kk0 + k][lane] = fmaxf(h[k], 0.f);
  }
  __syncthreads();                        // all 16 waves

  // ---- epilogue phase B: waves 0..3, o k-slices + output quarter ----
  if (wv < 4) {
    float o[8];
#pragma unroll
    for (int m = 0; m < 8; ++m) o[m] = b2[kk0 + m];
#pragma unroll
    for (int k = 0; k < D; ++k) {
      const float hv = hS[k][lane];       // lane-contiguous, conflict-free
      const float* __restrict__ w = W2 + (size_t)k * D + kk0;
#pragma unroll
      for (int m = 0; m < 8; ++m) o[m] = fmaf(hv, w[m], o[m]);
    }
    const float tnbc = red[0][lane];
    const float tcnt = red[1][lane];
    const bool lf = A.w > 0.f;
    const int nleaf = rsL[b * (ZBINS + 1) + ZBINS];  // scan carry = leaf total
    const bool cond = lf && (tnbc >= 2.0f) && (tcnt >= 1.0f) && (nleaf >= 10);

    float4* outr = (float4*)(out + (size_t)p * D + kk0);
#pragma unroll
    for (int i = 0; i < 2; ++i) {
      float4 v;
      if (cond) { v.x = o[4*i+0]; v.y = o[4*i+1]; v.z = o[4*i+2]; v.w = o[4*i+3]; }
      else      { v = eiS4[lane * 8 + (((kk0 >> 2) + i) ^ (lane & 7))]; }
      outr[i] = v;
    }
  }
}

// ---------------------------------------------------------------------------
extern "C" void kernel_launch(void* const* d_in, const int* in_sizes, int n_in,
                              void* d_out, int out_size, void* d_ws, size_t ws_size,
                              hipStream_t stream) {
  (void)in_sizes; (void)n_in; (void)out_size; (void)ws_size;
  const float* pts  = (const float*)d_in[0];
  const float* emb  = (const float*)d_in[1];
  const int*   leaf = (const int*)d_in[2];
  const float* W1   = (const float*)d_in[3];
  const float* b1   = (const float*)d_in[4];
  const float* W2   = (const float*)d_in[5];
  const float* b2   = (const float*)d_in[6];
  float* out = (float*)d_out;

  char* ws = (char*)d_ws;
  size_t off = 0;
  auto alloc = [&](size_t bytes) { void* r = ws + off; off = (off + bytes + 15) & ~(size_t)15; return r; };

  // +CHUNK rows of slack on j-side arrays: staging rounds up to 64-lane
  // granularity and may read past jhi; slack keeps those reads in-bounds.
  float4*   sortedA = (float4*)alloc((size_t)BN * 16);
  int*      permA   = (int*)alloc((size_t)BN * 4);
  float4*   pts4L   = (float4*)alloc((size_t)(BN + CHUNK) * 16);
  float*    invL    = (float*)alloc((size_t)(BN + CHUNK) * 4);
  float*    embL    = (float*)alloc((size_t)(BN + CHUNK) * D * 4);
  int*      rsA     = (int*)alloc(2 * (ZBINS + 1) * 4);
  int*      rsL     = (int*)alloc(2 * (ZBINS + 1) * 4);
  int*      curA    = (int*)alloc(2 * ZBINS * 4);
  int*      curL    = (int*)alloc(2 * ZBINS * 4);
  int*      histA   = (int*)alloc(2 * ZBINS * 4);   // histA..done contiguous
  int*      histL   = (int*)alloc(2 * ZBINS * 4);   //   -> single 8.2 KB memset
  unsigned* done    = (unsigned*)alloc(16);          // [0]=ticket [1]=scan flag

  hipMemsetAsync(histA, 0, 2 * (2 * ZBINS * 4) + 16, stream);
  prep_kernel<<<BN / BLOCK, BLOCK, 0, stream>>>(
      pts, emb, leaf, histA, histL, done, rsA, rsL, curA, curL,
      sortedA, permA, pts4L, invL, embL);
  pair_kernel<<<NGRP, PBLOCK, 0, stream>>>(
      sortedA, permA, pts4L, invL, embL, emb, rsL,
      W1, b1, W2, b2, out);
}